// Round 1
// baseline (511.368 us; speedup 1.0000x reference)
//
#include <hip/hip_runtime.h>
#include <hip/hip_fp16.h>
#include <hip/hip_cooperative_groups.h>

namespace cg = cooperative_groups;

#define NN 50000
#define NE 800000
#define EMB 64
#define MAXD 100
#define NBINS (2 * MAXD + 1)
#define SCALE 0.35355339059327373f
#define CAP 64                     // ELL row capacity; max deg ~45 for Poisson(16)
#define QBLK2 ((NN + 63) / 64)     // 782 qkv virtual blocks (64 nodes each)
#define EBLK (NE / 256)            // 3125 bucket virtual blocks
#define RBLK ((NBINS * EMB + 255) / 256)  // 51 relh-pack virtual blocks
#define TOTVB (QBLK2 + EBLK + RBLK)
#define NODEVB ((NN + 3) / 4)      // 12500 node virtual blocks (4 nodes each)

__global__ __launch_bounds__(256) void fill_kernel(float* __restrict__ out, long n, float val) {
    long i = (long)blockIdx.x * 256 + threadIdx.x;
    if (i < n) out[i] = val;
}

// ---- single persistent cooperative kernel: phase0 (cnt=0) | phase1 (qkv|bucket|relh)
//      | phase2 (gather+softmax+PV+GEMV). Two grid.sync()s replace two kernel
//      boundaries + one memset dispatch. Inner bodies are verbatim from the
//      previously-verified 2-kernel version.
__global__ __launch_bounds__(256, 4) void mega_kernel(
    const float* __restrict__ x,
    const float* __restrict__ Wq, const float* __restrict__ bq,
    const float* __restrict__ Wk, const float* __restrict__ bk,
    const float* __restrict__ Wv, const float* __restrict__ bv,
    const int* __restrict__ ei, const float* __restrict__ pos,
    const float* __restrict__ relk, const float* __restrict__ relv,
    __half* __restrict__ qh, __half2* __restrict__ kvh, __half2* __restrict__ relh,
    int* __restrict__ cnt, int* __restrict__ epack,
    const float* __restrict__ Wo, const float* __restrict__ bo,
    float* __restrict__ out)
{
    __shared__ float xs[64][EMB];   // 16 KB; phase2 aliases ys/ps/eps onto it
    int t = threadIdx.x;
    int NB = gridDim.x;
    cg::grid_group grid = cg::this_grid();

    // ---- phase 0: zero per-row counters (replaces hipMemsetAsync dispatch)
    for (int z = blockIdx.x * 256 + t; z < NN; z += NB * 256) cnt[z] = 0;
    __threadfence();    // agent-scope: wbl2 so bucket atomics (coherence point) see zeros
    grid.sync();

    // ---- phase 1: qkv | bucket | relh over virtual block ids
    for (int vb = blockIdx.x; vb < TOTVB; vb += NB) {
        if (vb < QBLK2) {
            // ---- QKV: 64 nodes/vblock; each wave computes 16 nodes sharing W loads
            int nodeBase = vb * 64;
            int fbase = nodeBase * EMB;
#pragma unroll
            for (int it = 0; it < 4; it++) {
                int idx4 = it * 256 + t;            // 1024 float4s = 64 nodes x 64 f
                float4 xv = make_float4(0.f, 0.f, 0.f, 0.f);
                const float* xp = x + fbase + idx4 * 4;
                if (fbase + idx4 * 4 < NN * EMB) {  // NT builtin: scalar pointers only
                    xv.x = __builtin_nontemporal_load(xp + 0);
                    xv.y = __builtin_nontemporal_load(xp + 1);
                    xv.z = __builtin_nontemporal_load(xp + 2);
                    xv.w = __builtin_nontemporal_load(xp + 3);
                }
                ((float4*)xs)[idx4] = xv;           // consecutive lanes -> consecutive addr
            }
            __syncthreads();
            int ln = t >> 6, c = t & 63;
            int n0 = ln * 16;
            float bqc = bq[c], bkc = bk[c], bvc = bv[c];
            float aq[16], ak[16], av[16];
#pragma unroll
            for (int n = 0; n < 16; n++) { aq[n] = bqc; ak[n] = bkc; av[n] = bvc; }
            for (int i4 = 0; i4 < EMB; i4 += 4) {
                float wq0 = Wq[(i4 + 0) * EMB + c], wq1 = Wq[(i4 + 1) * EMB + c],
                      wq2 = Wq[(i4 + 2) * EMB + c], wq3 = Wq[(i4 + 3) * EMB + c];
                float wk0 = Wk[(i4 + 0) * EMB + c], wk1 = Wk[(i4 + 1) * EMB + c],
                      wk2 = Wk[(i4 + 2) * EMB + c], wk3 = Wk[(i4 + 3) * EMB + c];
                float wv0 = Wv[(i4 + 0) * EMB + c], wv1 = Wv[(i4 + 1) * EMB + c],
                      wv2 = Wv[(i4 + 2) * EMB + c], wv3 = Wv[(i4 + 3) * EMB + c];
#pragma unroll
                for (int n = 0; n < 16; n++) {
                    float4 xv = *(const float4*)&xs[n0 + n][i4];  // wave-uniform broadcast
                    aq[n] += xv.x * wq0 + xv.y * wq1 + xv.z * wq2 + xv.w * wq3;
                    ak[n] += xv.x * wk0 + xv.y * wk1 + xv.z * wk2 + xv.w * wk3;
                    av[n] += xv.x * wv0 + xv.y * wv1 + xv.z * wv2 + xv.w * wv3;
                }
            }
#pragma unroll
            for (int n = 0; n < 16; n++) {
                int gnode = nodeBase + n0 + n;
                if (gnode < NN) {
                    qh[gnode * EMB + c] = __float2half(aq[n]);
                    kvh[gnode * EMB + c] = __floats2half2_rn(ak[n], av[n]);
                }
            }
            __syncthreads();   // xs reuse safety if this block gets another QKV vb
        } else if (vb < QBLK2 + EBLK) {
            // ---- bucket: one pass builds padded-ELL adjacency; entry = (col<<9)|bin
            int e = (vb - QBLK2) * 256 + t;
            int row = __builtin_nontemporal_load(ei + e);
            int col = __builtin_nontemporal_load(ei + NE + e);
            float dx = pos[row * 3 + 0] - pos[col * 3 + 0];
            float dy = pos[row * 3 + 1] - pos[col * 3 + 1];
            float dz = pos[row * 3 + 2] - pos[col * 3 + 2];
            float dist = sqrtf(dx * dx + dy * dy + dz * dz);
            int bin = (int)(dist * 10.0f);         // dist >= 0; trunc = .astype(int32)
            bin = bin > MAXD ? MAXD : bin;
            bin += MAXD;
            int rank = atomicAdd(&cnt[row], 1);
            if (rank < CAP) epack[(row << 6) + rank] = (col << 9) | bin;
        } else {
            // ---- pack rel tables into half2 (rk, rv)
            int idx = (vb - QBLK2 - EBLK) * 256 + t;
            if (idx < NBINS * EMB) relh[idx] = __floats2half2_rn(relk[idx], relv[idx]);
        }
    }
    __threadfence();    // agent-scope release: flush qh/kvh/relh/epack/cnt
    grid.sync();        // + acquire-invalidate so phase2 readers see fresh lines

    // ---- phase 2: node gather+softmax+PV (pair-unrolled, depth-6 prefetch) -> GEMV
    {
        float (*ys)[EMB]     = reinterpret_cast<float (*)[EMB]>(&xs[0][0]);      // 1 KB
        float (*ps)[4][EMB]  = reinterpret_cast<float (*)[4][EMB]>(&xs[4][0]);   // 4 KB @ +1 KB
        int   (*eps)[CAP+16] = reinterpret_cast<int (*)[CAP+16]>(&xs[20][0]);    // 1.25 KB @ +5 KB
        int ln = t >> 6, i = t & 63;
        for (int vb = blockIdx.x; vb < NODEVB; vb += NB) {
            int node = vb * 4 + ln;
            float num = 0.0f, den = 0.0f;
            if (node < NN) {
                float qi = __half2float(qh[node * EMB + i]);
                int deg = cnt[node];
                if (deg > CAP) deg = CAP;
                if (deg > 0) {
                    // predicated stage: only occupied slots fetched
                    eps[ln][i] = (i < deg) ? epack[(node << 6) + i] : 0;
                    if (i < 16) eps[ln][CAP + i] = 0;
                    // s.x = k+rk, s.y = v+rv (packed half add); index masks keep any
                    // garbage/pad reads inside ws (col<=0xFFFF, bin<=511)
                    auto FETCH = [&](int j, float2& s) {
                        int pk = eps[ln][j];               // wave-uniform LDS broadcast
                        __half2 kk = kvh[((((unsigned)pk >> 9) & 0xFFFF) << 6) + i];
                        __half2 rr = relh[(((unsigned)pk & 511) << 6) + i];
                        s = __half22float2(__hadd2(kk, rr));
                    };
                    float2 c0, c1, n0, n1, m0, m1;
                    FETCH(0, c0); FETCH(1, c1); FETCH(2, n0);
                    FETCH(3, n1); FETCH(4, m0); FETCH(5, m1);
                    for (int g = 0; g < deg; g += 2) {
                        float2 p0, p1;
                        FETCH(g + 6, p0);
                        FETCH(g + 7, p1);
                        float pA = qi * c0.x;
                        bool two = (g + 1 < deg);             // wave-uniform
                        float pB = two ? qi * c1.x : 0.0f;
                        pA += __shfl_xor(pA, 1, 64);
                        pB += __shfl_xor(pB, 1, 64);
                        pA += __shfl_xor(pA, 2, 64);
                        pB += __shfl_xor(pB, 2, 64);
                        pA += __shfl_xor(pA, 4, 64);
                        pB += __shfl_xor(pB, 4, 64);
                        float eA = __expf(pA * SCALE);        // softmax shift-invariant
                        float eB = __expf(pB * SCALE);
                        den += eA;
                        num += eA * c0.y;
                        if (two) {
                            den += eB;
                            num += eB * c1.y;
                        }
                        c0 = n0; c1 = n1; n0 = m0; n1 = m1; m0 = p0; m1 = p1;
                    }
                }
            }
            ys[ln][i] = (den > 0.0f) ? num / den : 0.0f;
            __syncthreads();
            // epilogue: wave ln covers i-range [16*ln,16*ln+16) for all 4 nodes
            float acc0 = 0.f, acc1 = 0.f, acc2 = 0.f, acc3 = 0.f;
#pragma unroll 4
            for (int r = 0; r < 16; r++) {
                int ii = ln * 16 + r;
                float w = Wo[ii * EMB + i];
                acc0 += ys[0][ii] * w;
                acc1 += ys[1][ii] * w;
                acc2 += ys[2][ii] * w;
                acc3 += ys[3][ii] * w;
            }
            ps[ln][0][i] = acc0; ps[ln][1][i] = acc1; ps[ln][2][i] = acc2; ps[ln][3][i] = acc3;
            __syncthreads();
            if (node < NN)
                out[node * EMB + i] = bo[i] + ps[0][ln][i] + ps[1][ln][i] + ps[2][ln][i] + ps[3][ln][i];
            // no trailing barrier needed: next iteration's pre-sync writes (eps[ln], ys[ln])
            // are disjoint from ps, and ps is only rewritten after the next __syncthreads()
        }
    }
}

extern "C" void kernel_launch(void* const* d_in, const int* in_sizes, int n_in,
                              void* d_out, int out_size, void* d_ws, size_t ws_size,
                              hipStream_t stream) {
    float* out = (float*)d_out;
    long on = out_size;
    int ogrid = (int)((on + 255) / 256);

    if (n_in != 13) { fill_kernel<<<ogrid, 256, 0, stream>>>(out, on, 3000.0f); return; }

    const float* x    = (const float*)d_in[0];
    const int*   ei   = (const int*)d_in[1];
    const float* pos  = (const float*)d_in[2];
    const float* Wq   = (const float*)d_in[3];
    const float* bq   = (const float*)d_in[4];
    const float* Wk   = (const float*)d_in[5];
    const float* bk   = (const float*)d_in[6];
    const float* Wv   = (const float*)d_in[7];
    const float* bv   = (const float*)d_in[8];
    const float* relk = (const float*)d_in[9];
    const float* relv = (const float*)d_in[10];
    const float* Wo   = (const float*)d_in[11];
    const float* bo   = (const float*)d_in[12];

    __half*  qh   = (__half*)d_ws;                       // NN*EMB half (6.4 MB)
    __half2* kvh  = (__half2*)(qh + (long)NN * EMB);     // NN*EMB half2 (12.8 MB)
    __half2* relh = kvh + (long)NN * EMB;                // NBINS*EMB half2
    int*     cnt  = (int*)(relh + NBINS * EMB);          // NN
    int*     epack= cnt + NN;                            // NN*CAP (padded ELL)

    size_t need = (size_t)((char*)(epack + (long)NN * CAP + 64) - (char*)d_ws);
    if (ws_size < need) { fill_kernel<<<ogrid, 256, 0, stream>>>(out, on, 1000.0f); return; }

    // co-residency-safe grid size for cooperative launch (pure host query, capture-safe)
    static int maxb = -1;
    if (maxb < 0) {
        int r = 0;
        if (hipOccupancyMaxActiveBlocksPerMultiprocessor(&r, mega_kernel, 256, 0) != hipSuccess || r < 1)
            r = 1;
        maxb = r;
    }
    int nb = maxb * 256;            // 256 CUs on MI355X
    if (nb > 2048) nb = 2048;       // 8 blocks/CU = 32 waves/CU hardware cap

    void* args[] = {
        (void*)&x,
        (void*)&Wq, (void*)&bq, (void*)&Wk, (void*)&bk, (void*)&Wv, (void*)&bv,
        (void*)&ei, (void*)&pos, (void*)&relk, (void*)&relv,
        (void*)&qh, (void*)&kvh, (void*)&relh,
        (void*)&cnt, (void*)&epack,
        (void*)&Wo, (void*)&bo,
        (void*)&out
    };
    (void)hipLaunchCooperativeKernel(reinterpret_cast<const void*>(&mega_kernel),
                                     dim3(nb), dim3(256), args, 0, stream);
}

// Round 2
// 197.452 us; speedup vs baseline: 2.5898x; 2.5898x over previous
//
#include <hip/hip_runtime.h>
#include <hip/hip_fp16.h>

#define NN 50000
#define NE 800000
#define EMB 64
#define MAXD 100
#define NBINS (2 * MAXD + 1)
#define SCALE 0.35355339059327373f
#define CAP 64                     // ELL row capacity; max deg ~45 for Poisson(16)
#define QBLK2 ((NN + 63) / 64)     // 782 qkv blocks (64 nodes each)
#define EBLK (NE / 256)            // 3125 edge chunks (256 edges each)
#define EBLK8 (EBLK * 8)           // x8 row-partitioned bucket blocks (XCD-local epack)
#define RBLK ((NBINS * EMB + 255) / 256)  // 51 relh-pack blocks
#define ROWS_PER_PART 6250         // 50000 / 8 partitions

__global__ __launch_bounds__(256) void fill_kernel(float* __restrict__ out, long n, float val) {
    long i = (long)blockIdx.x * 256 + threadIdx.x;
    if (i < n) out[i] = val;
}

// ---- fused pre-pass: qkv (64-node tiles) | bucket (row-partitioned x8) | relh-pack.
//      Bucket partitioning: each 256-edge chunk is covered by 8 consecutive blocks
//      (round-robin onto the 8 XCDs); block p handles rows [p*6250,(p+1)*6250) only,
//      so each XCD's epack scatter working set is 1.6 MB -> L2-resident -> writeback
//      collapses from ~16x/line to ~compulsory.
__global__ __launch_bounds__(256) void fused_kernel(
    const float* __restrict__ x,
    const float* __restrict__ Wq, const float* __restrict__ bq,
    const float* __restrict__ Wk, const float* __restrict__ bk,
    const float* __restrict__ Wv, const float* __restrict__ bv,
    const int* __restrict__ ei, const float* __restrict__ pos,
    const float* __restrict__ relk, const float* __restrict__ relv,
    __half* __restrict__ qh, __half2* __restrict__ kvh, __half2* __restrict__ relh,
    int* __restrict__ cnt, int* __restrict__ epack)
{
    __shared__ float xs[64][EMB];   // 16 KB, linear
    int b = blockIdx.x, t = threadIdx.x;
    if (b < QBLK2) {
        // ---- QKV: 64 nodes/block; each wave computes 16 nodes sharing W loads
        int nodeBase = b * 64;
        int fbase = nodeBase * EMB;
#pragma unroll
        for (int it = 0; it < 4; it++) {
            int idx4 = it * 256 + t;            // 1024 float4s = 64 nodes x 64 f
            float4 xv = make_float4(0.f, 0.f, 0.f, 0.f);
            const float* xp = x + fbase + idx4 * 4;
            if (fbase + idx4 * 4 < NN * EMB) {  // NT builtin: scalar pointers only
                xv.x = __builtin_nontemporal_load(xp + 0);
                xv.y = __builtin_nontemporal_load(xp + 1);
                xv.z = __builtin_nontemporal_load(xp + 2);
                xv.w = __builtin_nontemporal_load(xp + 3);
            }
            ((float4*)xs)[idx4] = xv;           // consecutive lanes -> consecutive addr
        }
        __syncthreads();
        int ln = t >> 6, c = t & 63;
        int n0 = ln * 16;
        float bqc = bq[c], bkc = bk[c], bvc = bv[c];
        float aq[16], ak[16], av[16];
#pragma unroll
        for (int n = 0; n < 16; n++) { aq[n] = bqc; ak[n] = bkc; av[n] = bvc; }
        for (int i4 = 0; i4 < EMB; i4 += 4) {
            float wq0 = Wq[(i4 + 0) * EMB + c], wq1 = Wq[(i4 + 1) * EMB + c],
                  wq2 = Wq[(i4 + 2) * EMB + c], wq3 = Wq[(i4 + 3) * EMB + c];
            float wk0 = Wk[(i4 + 0) * EMB + c], wk1 = Wk[(i4 + 1) * EMB + c],
                  wk2 = Wk[(i4 + 2) * EMB + c], wk3 = Wk[(i4 + 3) * EMB + c];
            float wv0 = Wv[(i4 + 0) * EMB + c], wv1 = Wv[(i4 + 1) * EMB + c],
                  wv2 = Wv[(i4 + 2) * EMB + c], wv3 = Wv[(i4 + 3) * EMB + c];
#pragma unroll
            for (int n = 0; n < 16; n++) {
                float4 xv = *(const float4*)&xs[n0 + n][i4];  // wave-uniform broadcast
                aq[n] += xv.x * wq0 + xv.y * wq1 + xv.z * wq2 + xv.w * wq3;
                ak[n] += xv.x * wk0 + xv.y * wk1 + xv.z * wk2 + xv.w * wk3;
                av[n] += xv.x * wv0 + xv.y * wv1 + xv.z * wv2 + xv.w * wv3;
            }
        }
#pragma unroll
        for (int n = 0; n < 16; n++) {
            int gnode = nodeBase + n0 + n;
            if (gnode < NN) {
                qh[gnode * EMB + c] = __float2half(aq[n]);
                kvh[gnode * EMB + c] = __floats2half2_rn(ak[n], av[n]);
            }
        }
    } else if (b < QBLK2 + EBLK8) {
        // ---- bucket: 8 blocks per chunk; block (b&7) takes rows in its 1/8 range.
        //      entry = (col<<9)|bin. ei reads NOT nontemporal (reused by 8 blocks).
        int j = b - QBLK2;
        int chunk = j >> 3;
        int p = b & 7;                         // consecutive bids -> distinct XCDs (heuristic)
        int e = chunk * 256 + t;
        int row = ei[e];
        if (row / ROWS_PER_PART == p) {        // exactly one covering block takes each edge
            int col = ei[NE + e];
            float dx = pos[row * 3 + 0] - pos[col * 3 + 0];
            float dy = pos[row * 3 + 1] - pos[col * 3 + 1];
            float dz = pos[row * 3 + 2] - pos[col * 3 + 2];
            float dist = sqrtf(dx * dx + dy * dy + dz * dz);
            int bin = (int)(dist * 10.0f);     // dist >= 0; trunc = .astype(int32)
            bin = bin > MAXD ? MAXD : bin;
            bin += MAXD;
            int rank = atomicAdd(&cnt[row], 1);
            if (rank < CAP) epack[(row << 6) + rank] = (col << 9) | bin;
        }
    } else {
        // ---- pack rel tables into half2 (rk, rv)
        int idx = (b - QBLK2 - EBLK8) * 256 + t;
        if (idx < NBINS * EMB) relh[idx] = __floats2half2_rn(relk[idx], relv[idx]);
    }
}

// ---- node: deg-predicated LDS-stage of edge list -> gather+softmax+PV
//      (pair-unrolled, depth-6 prefetch, masked garbage-safe) -> fused GEMV.
__global__ __launch_bounds__(256) void node_kernel(
    const int* __restrict__ cnt, const int* __restrict__ epack,
    const __half* __restrict__ qh, const __half2* __restrict__ kvh,
    const __half2* __restrict__ relh,
    const float* __restrict__ Wo, const float* __restrict__ bo,
    float* __restrict__ out)
{
    __shared__ float ys[4][EMB];
    __shared__ float ps[4][4][EMB];
    __shared__ int eps[4][CAP + 16];   // staged edges + pad for prefetch over-reads
    int t = threadIdx.x, ln = t >> 6, i = t & 63;
    int node = blockIdx.x * 4 + ln;
    float num = 0.0f, den = 0.0f;
    if (node < NN) {
        float qi = __half2float(qh[node * EMB + i]);
        int deg = cnt[node];
        if (deg > CAP) deg = CAP;
        if (deg > 0) {
            // predicated stage: only occupied slots fetched (-9.6 MB vs full row)
            eps[ln][i] = (i < deg) ? epack[(node << 6) + i] : 0;
            if (i < 16) eps[ln][CAP + i] = 0;
            // s.x = k+rk, s.y = v+rv (packed half add); index masks keep any
            // garbage/pad reads inside ws (col<=0xFFFF, bin<=511)
            auto FETCH = [&](int j, float2& s) {
                int pk = eps[ln][j];               // wave-uniform LDS broadcast
                __half2 kk = kvh[((((unsigned)pk >> 9) & 0xFFFF) << 6) + i];
                __half2 rr = relh[(((unsigned)pk & 511) << 6) + i];
                s = __half22float2(__hadd2(kk, rr));
            };
            float2 c0, c1, n0, n1, m0, m1;
            FETCH(0, c0); FETCH(1, c1); FETCH(2, n0);
            FETCH(3, n1); FETCH(4, m0); FETCH(5, m1);
            for (int g = 0; g < deg; g += 2) {
                float2 p0, p1;
                FETCH(g + 6, p0);
                FETCH(g + 7, p1);
                float pA = qi * c0.x;
                bool two = (g + 1 < deg);             // wave-uniform
                float pB = two ? qi * c1.x : 0.0f;
                pA += __shfl_xor(pA, 1, 64);
                pB += __shfl_xor(pB, 1, 64);
                pA += __shfl_xor(pA, 2, 64);
                pB += __shfl_xor(pB, 2, 64);
                pA += __shfl_xor(pA, 4, 64);
                pB += __shfl_xor(pB, 4, 64);
                float eA = __expf(pA * SCALE);        // softmax shift-invariant
                float eB = __expf(pB * SCALE);
                den += eA;
                num += eA * c0.y;
                if (two) {
                    den += eB;
                    num += eB * c1.y;
                }
                c0 = n0; c1 = n1; n0 = m0; n1 = m1; m0 = p0; m1 = p1;
            }
        }
    }
    ys[ln][i] = (den > 0.0f) ? num / den : 0.0f;
    __syncthreads();
    // epilogue: wave ln covers i-range [16*ln,16*ln+16) for all 4 nodes (shares Wo loads)
    float acc0 = 0.f, acc1 = 0.f, acc2 = 0.f, acc3 = 0.f;
#pragma unroll 4
    for (int r = 0; r < 16; r++) {
        int ii = ln * 16 + r;
        float w = Wo[ii * EMB + i];
        acc0 += ys[0][ii] * w;
        acc1 += ys[1][ii] * w;
        acc2 += ys[2][ii] * w;
        acc3 += ys[3][ii] * w;
    }
    ps[ln][0][i] = acc0; ps[ln][1][i] = acc1; ps[ln][2][i] = acc2; ps[ln][3][i] = acc3;
    __syncthreads();
    if (node >= NN) return;
    out[node * EMB + i] = bo[i] + ps[0][ln][i] + ps[1][ln][i] + ps[2][ln][i] + ps[3][ln][i];
}

extern "C" void kernel_launch(void* const* d_in, const int* in_sizes, int n_in,
                              void* d_out, int out_size, void* d_ws, size_t ws_size,
                              hipStream_t stream) {
    float* out = (float*)d_out;
    long on = out_size;
    int ogrid = (int)((on + 255) / 256);

    if (n_in != 13) { fill_kernel<<<ogrid, 256, 0, stream>>>(out, on, 3000.0f); return; }

    const float* x    = (const float*)d_in[0];
    const int*   ei   = (const int*)d_in[1];
    const float* pos  = (const float*)d_in[2];
    const float* Wq   = (const float*)d_in[3];
    const float* bq   = (const float*)d_in[4];
    const float* Wk   = (const float*)d_in[5];
    const float* bk   = (const float*)d_in[6];
    const float* Wv   = (const float*)d_in[7];
    const float* bv   = (const float*)d_in[8];
    const float* relk = (const float*)d_in[9];
    const float* relv = (const float*)d_in[10];
    const float* Wo   = (const float*)d_in[11];
    const float* bo   = (const float*)d_in[12];

    __half*  qh   = (__half*)d_ws;                       // NN*EMB half (6.4 MB)
    __half2* kvh  = (__half2*)(qh + (long)NN * EMB);     // NN*EMB half2 (12.8 MB)
    __half2* relh = kvh + (long)NN * EMB;                // NBINS*EMB half2
    int*     cnt  = (int*)(relh + NBINS * EMB);          // NN
    int*     epack= cnt + NN;                            // NN*CAP (padded ELL)

    size_t need = (size_t)((char*)(epack + (long)NN * CAP + 64) - (char*)d_ws);
    if (ws_size < need) { fill_kernel<<<ogrid, 256, 0, stream>>>(out, on, 1000.0f); return; }

    (void)hipMemsetAsync(cnt, 0, (size_t)NN * sizeof(int), stream);   // cnt only (200 KB)
    fused_kernel<<<QBLK2 + EBLK8 + RBLK, 256, 0, stream>>>(
        x, Wq, bq, Wk, bk, Wv, bv, ei, pos, relk, relv, qh, kvh, relh, cnt, epack);
    node_kernel<<<(NN + 3) / 4, 256, 0, stream>>>(cnt, epack, qh, kvh, relh, Wo, bo, out);
}